// Round 11
// baseline (245.015 us; speedup 1.0000x reference)
//
#include <hip/hip_runtime.h>
#include <math.h>

typedef unsigned short u16;
typedef __attribute__((ext_vector_type(8))) short bf16x8;
typedef __attribute__((ext_vector_type(4))) float f32x4;

#define ADJ_CAP 96   // padded CSR row capacity; Poisson(16) tail @96 ~ 0

__device__ __forceinline__ u16 f2b(float f) {
    union { float f; unsigned u; } v; v.f = f;
    unsigned r = (v.u + 0x7FFF + ((v.u >> 16) & 1)) >> 16;
    return (u16)r;
}
__device__ __forceinline__ float b2f(u16 h) {
    union { unsigned u; float f; } v; v.u = (unsigned)h << 16;
    return v.f;
}
__device__ __forceinline__ float u2f(unsigned u) {
    union { unsigned u; float f; } v; v.u = u;
    return v.f;
}
__device__ __forceinline__ float fsig(float x) { return 1.f / (1.f + __expf(-x)); }
__device__ __forceinline__ float ftanh(float x) {
    float e = __expf(2.f * x);
    return 1.f - 2.f / (e + 1.f);
}

__device__ __forceinline__ void gll16(const void* g, void* l) {
    __builtin_amdgcn_global_load_lds(
        (const __attribute__((address_space(1))) void*)g,
        (__attribute__((address_space(3))) void*)l, 16, 0, 0);
}

// ---------------- weight prep helper ----------------
__device__ __forceinline__ void conv_chunk(const float* __restrict__ src,
                                           u16* __restrict__ dst, int c, int NC) {
    int sl = c / NC, n = c - sl * NC;
    u16 tmp[8];
#pragma unroll
    for (int i = 0; i < 8; ++i) tmp[i] = f2b(src[(size_t)(sl * 8 + i) * NC + n]);
    *(uint4*)(dst + (size_t)c * 8) = *(const uint4*)tmp;
}

// ---------------- fused prologue: CSR build + weight prep + x->bf16 --------
__global__ void k_pro(const int* __restrict__ ei, int* __restrict__ cnt,
                      u16* __restrict__ adj, int E, int N,
                      const float* __restrict__ W1, const float* __restrict__ W2,
                      const float* __restrict__ Wih, const float* __restrict__ Whh,
                      const float* __restrict__ lW1, const float* __restrict__ lW2,
                      u16* __restrict__ tW1, u16* __restrict__ tW2,
                      u16* __restrict__ tGRU,
                      u16* __restrict__ tlW1, u16* __restrict__ tlW2, int L,
                      const float* __restrict__ x, u16* __restrict__ xb, int n8) {
    const int EB = (E + 255) >> 8;
    const int nwc = L * 4096 + 12288 + 3072;
    const int WB = (nwc + 255) >> 8;
    int b = blockIdx.x;
    if (b < EB * 8) {
        const int part = b & 7, chunk = b >> 3;
        const int span = (N + 7) >> 3;
        const int nlo = part * span;
        const int nhi = (nlo + span < N) ? nlo + span : N;
        int e = chunk * 256 + threadIdx.x;
        if (e < E) {
            int s = ei[e], d = ei[E + e];
            if (s >= nlo && s < nhi) {
                int p = atomicAdd(&cnt[s], 1);
                adj[(size_t)s * ADJ_CAP + p] = (u16)d;
            }
            if (d >= nlo && d < nhi) {
                int q = atomicAdd(&cnt[d], 1);
                adj[(size_t)d * ADJ_CAP + q] = (u16)s;
            }
        }
        return;
    }
    b -= EB * 8;
    if (b < WB) {
        int c = b * 256 + threadIdx.x;
        if (c >= nwc) return;
        if (c < L * 2048) { int l = c >> 11; conv_chunk(W1 + (size_t)l * 16384, tW1 + (size_t)l * 16384, c & 2047, 128); return; }
        c -= L * 2048;
        if (c < L * 2048) { int l = c >> 11; conv_chunk(W2 + (size_t)l * 16384, tW2 + (size_t)l * 16384, c & 2047, 128); return; }
        c -= L * 2048;
        if (c < 12288) {
            int s = c >> 9, r = c & 511;
            int q = r >> 7, mat = (r >> 6) & 1, cc = r & 63;
            int h = s / 12, s2 = s % 12, kc = s2 / 3, g = s2 % 3;
            int ocol = g * 128 + h * 64 + cc;
            const float* src = mat ? Whh : Wih;
            int kb = (kc * 4 + q) * 8;
            u16 tmp[8];
#pragma unroll
            for (int e = 0; e < 8; ++e) tmp[e] = f2b(src[(size_t)(kb + e) * 384 + ocol]);
            *(uint4*)(tGRU + (size_t)c * 8) = *(const uint4*)tmp;
            return;
        }
        c -= 12288;
        if (c < 2048) { conv_chunk(lW1, tlW1, c, 128); return; }
        c -= 2048;
        if (c < 1024) { conv_chunk(lW2, tlW2, c, 64); return; }
        return;
    }
    b -= WB;
    {
        int i = b * 256 + threadIdx.x;
        if (i < n8) {
            float4 a = *(const float4*)(x + (size_t)i * 8);
            float4 bb = *(const float4*)(x + (size_t)i * 8 + 4);
            u16 t[8] = {f2b(a.x), f2b(a.y), f2b(a.z), f2b(a.w),
                        f2b(bb.x), f2b(bb.y), f2b(bb.z), f2b(bb.w)};
            *(uint4*)(xb + (size_t)i * 8) = *(const uint4*)t;
        }
    }
}

// ---------------- aggregation: 16 lanes/row, 4 neighbors in parallel -------
__global__ __launch_bounds__(256) void k_agg(const u16* __restrict__ xb,
                                             const u16* __restrict__ adj,
                                             const int* __restrict__ cnt,
                                             const float* __restrict__ aW,
                                             const float* __restrict__ ab,
                                             u16* __restrict__ comb, int N) {
    int n = blockIdx.x * 4 + (threadIdx.x >> 6);
    if (n >= N) return;
    int l = threadIdx.x & 63;
    int grp = l >> 4;            // neighbor slot 0..3
    int f0 = (l & 15) * 8;       // 8 features per lane
    int beg = n * ADJ_CAP, deg = cnt[n], end = beg + deg;
    float s[8], m[8];
#pragma unroll
    for (int i = 0; i < 8; ++i) { s[i] = 0.f; m[i] = -3.402823e38f; }

    auto acc8 = [&](uint4 v) {
        unsigned d[4] = {v.x, v.y, v.z, v.w};
#pragma unroll
        for (int i = 0; i < 4; ++i) {
            float a0 = u2f(d[i] << 16);
            float a1 = u2f(d[i] & 0xFFFF0000u);
            s[2 * i] += a0;     m[2 * i] = fmaxf(m[2 * i], a0);
            s[2 * i + 1] += a1; m[2 * i + 1] = fmaxf(m[2 * i + 1], a1);
        }
    };

    int j = beg + grp;
    for (; j + 4 < end; j += 8) {
        int a0 = adj[j], a1 = adj[j + 4];
        uint4 v0 = *(const uint4*)(xb + (size_t)a0 * 128 + f0);
        uint4 v1 = *(const uint4*)(xb + (size_t)a1 * 128 + f0);
        acc8(v0);
        acc8(v1);
    }
    if (j < end) {
        int a = adj[j];
        uint4 v = *(const uint4*)(xb + (size_t)a * 128 + f0);
        acc8(v);
    }
    // reduce across 4 neighbor groups
#pragma unroll
    for (int i = 0; i < 8; ++i) {
        s[i] += __shfl_xor(s[i], 16);
        s[i] += __shfl_xor(s[i], 32);
        m[i] = fmaxf(m[i], __shfl_xor(m[i], 16));
        m[i] = fmaxf(m[i], __shfl_xor(m[i], 32));
    }
    if (deg == 0) {
#pragma unroll
        for (int i = 0; i < 8; ++i) m[i] = 0.f;
    }
    float p0 = 0.f, p1 = 0.f;
#pragma unroll
    for (int i = 0; i < 8; ++i) {
        float2 wS = *(const float2*)(aW + (size_t)(f0 + i) * 2);
        float2 wM = *(const float2*)(aW + (size_t)(128 + f0 + i) * 2);
        p0 += s[i] * wS.x + m[i] * wM.x;
        p1 += s[i] * wS.y + m[i] * wM.y;
    }
#pragma unroll
    for (int o = 8; o; o >>= 1) { p0 += __shfl_xor(p0, o); p1 += __shfl_xor(p1, o); }
    p0 += ab[0]; p1 += ab[1];
    float pm = fmaxf(p0, p1);
    float ea = __expf(p0 - pm), eb = __expf(p1 - pm);
    float w0 = ea / (ea + eb), w1 = 1.f - w0;
    if (grp == 0) {
        uint4 xv = *(const uint4*)(xb + (size_t)n * 128 + f0);
        unsigned xs[4] = {xv.x, xv.y, xv.z, xv.w};
        unsigned dw[4];
#pragma unroll
        for (int i = 0; i < 4; ++i) {
            float xlo = u2f(xs[i] << 16), xhi = u2f(xs[i] & 0xFFFF0000u);
            float olo = xlo + w0 * s[2 * i] + w1 * m[2 * i];
            float ohi = xhi + w0 * s[2 * i + 1] + w1 * m[2 * i + 1];
            dw[i] = (unsigned)f2b(olo) | ((unsigned)f2b(ohi) << 16);
        }
        uint4 o4 = make_uint4(dw[0], dw[1], dw[2], dw[3]);
        *(uint4*)(comb + (size_t)n * 128 + f0) = o4;
    }
}

// ---------------- fused layer, counted-vmcnt pipeline (40 KB LDS) ----------
// R7/R9 structure + T5 setprio. FIN=true additionally fuses the final MLP:
// h' stays in regs -> x_s -> 6 more pipeline stages (lW1 x4, lW2 x2) -> out.
template <bool H0, bool FIN>
__global__ __launch_bounds__(256, 4) void k_layer(
    const u16* __restrict__ Cb, const u16* __restrict__ Hb,
    const u16* __restrict__ W1t, const float* __restrict__ b1,
    const u16* __restrict__ W2t, const float* __restrict__ b2,
    const float* __restrict__ gam, const float* __restrict__ bet,
    const u16* __restrict__ tG,
    const float* __restrict__ bih, const float* __restrict__ bhh,
    u16* __restrict__ HnB,
    const u16* __restrict__ lW1t, const float* __restrict__ lb1,
    const u16* __restrict__ lW2t, const float* __restrict__ lb2,
    float* __restrict__ out, int M) {
    __shared__ __align__(16) u16 x_s[64 * 16 * 8];   // 16 KB: comb -> z1 -> z -> h' -> y1
    __shared__ __align__(16) u16 b_s[3][4096];       // 3 x 8 KB weight ring
    const int t = threadIdx.x;
    const int m0 = blockIdx.x * 64;
    const int wid = t >> 6, lane = t & 63, lo = lane & 15, hi = lane >> 4;
    const int arow = 16 * wid + lo;
    const int LAST = FIN ? 37 : 31;

    auto issue = [&](int s) {   // stage 8 KB: 2 gll16 per wave
        const u16* g;
        if (s < 4)                 g = W1t + (size_t)s * 4096;
        else if (s < 8)            g = W2t + (size_t)(s - 4) * 4096;
        else if (!FIN || s < 32)   g = tG + (size_t)(s - 8) * 4096;
        else if (s < 36)           g = lW1t + (size_t)(s - 32) * 4096;
        else                       g = lW2t + (size_t)(s - 36) * 4096;
        char* l = (char*)b_s[s % 3] + wid * 2048;
        const char* gp = (const char*)g + wid * 2048 + lane * 16;
        gll16(gp, l);
        gll16(gp + 1024, l + 1024);
    };

    // ---- prologue
    float b1r[8], g2r[8], t2r[8];
#pragma unroll
    for (int j = 0; j < 8; ++j) {
        int c = 16 * j + lo;
        b1r[j] = b1[c];
        float gv = gam[c];
        g2r[j] = gv;
        t2r[j] = b2[c] * gv + bet[c];
    }
#pragma unroll
    for (int i = 0; i < 4; ++i) {
        int off = (i * 4 + wid) * 1024;
        int row = (off >> 8) + (lane >> 4);
        int sl = lane & 15;
        int gr = m0 + row; gr = gr < M ? gr : M - 1;
        gll16(Cb + (size_t)gr * 128 + ((sl ^ (row & 7)) * 8), (char*)x_s + off);
    }
    issue(0);
    issue(1);

    f32x4 acc[8];
#pragma unroll
    for (int j = 0; j < 8; ++j) acc[j] = (f32x4)0.f;

    // ---- GEMM1: phases 0..3
#pragma unroll
    for (int ks = 0; ks < 4; ++ks) {
        const int p = ks;
        asm volatile("s_waitcnt vmcnt(2)" ::: "memory");
        __builtin_amdgcn_s_barrier();
        issue(p + 2);
        bf16x8 af = *(const bf16x8*)&x_s[(arow * 16 + ((ks * 4 + hi) ^ (arow & 7))) * 8];
        const u16* buf = b_s[p % 3];
        __builtin_amdgcn_s_setprio(1);
#pragma unroll
        for (int j = 0; j < 8; ++j) {
            bf16x8 bf = *(const bf16x8*)&buf[((size_t)hi * 128 + 16 * j + lo) * 8];
            acc[j] = __builtin_amdgcn_mfma_f32_16x16x32_bf16(af, bf, acc[j], 0, 0, 0);
        }
        __builtin_amdgcn_s_setprio(0);
    }
#pragma unroll
    for (int j = 0; j < 8; ++j) {
        int c = 16 * j + lo;
#pragma unroll
        for (int q = 0; q < 4; ++q) {
            int row = 16 * wid + hi * 4 + q;
            float v = fmaxf(acc[j][q] + b1r[j], 0.f);
            int sl = c >> 3;
            x_s[(row * 16 + (sl ^ (row & 7))) * 8 + (c & 7)] = f2b(v);
        }
        acc[j] = (f32x4)0.f;
    }

    // ---- GEMM2: phases 4..7
#pragma unroll
    for (int ks = 0; ks < 4; ++ks) {
        const int p = 4 + ks;
        asm volatile("s_waitcnt vmcnt(2)" ::: "memory");
        __builtin_amdgcn_s_barrier();
        issue(p + 2);
        bf16x8 af = *(const bf16x8*)&x_s[(arow * 16 + ((ks * 4 + hi) ^ (arow & 7))) * 8];
        const u16* buf = b_s[p % 3];
        __builtin_amdgcn_s_setprio(1);
#pragma unroll
        for (int j = 0; j < 8; ++j) {
            bf16x8 bf = *(const bf16x8*)&buf[((size_t)hi * 128 + 16 * j + lo) * 8];
            acc[j] = __builtin_amdgcn_mfma_f32_16x16x32_bf16(af, bf, acc[j], 0, 0, 0);
        }
        __builtin_amdgcn_s_setprio(0);
    }
#pragma unroll
    for (int j = 0; j < 8; ++j) {
        int c = 16 * j + lo;
#pragma unroll
        for (int q = 0; q < 4; ++q) {
            int row = 16 * wid + hi * 4 + q;
            float v = acc[j][q] * g2r[j] + t2r[j];
            int sl = c >> 3;
            x_s[(row * 16 + (sl ^ (row & 7))) * 8 + (c & 7)] = f2b(v);
        }
    }
    bf16x8 hreg[4];
    if (!H0) {
        int gr = m0 + arow; gr = gr < M ? gr : M - 1;
#pragma unroll
        for (int kc = 0; kc < 4; ++kc)
            hreg[kc] = *(const bf16x8*)(Hb + (size_t)gr * 128 + (kc * 4 + hi) * 8);
    }

    // ---- GRU: phases 8..31
    f32x4 racc[4], uacc[4], nza[4], nha[4];
    float o_all[2][4][4];

    auto epi = [&](int h, float (&oo)[4][4]) {
#pragma unroll
        for (int ct = 0; ct < 4; ++ct) {
            int c = h * 64 + ct * 16 + lo;
            float b_r = bih[c] + bhh[c];
            float b_u = bih[c + 128] + bhh[c + 128];
            float b_in = bih[c + 256], b_hn = bhh[c + 256];
#pragma unroll
            for (int q = 0; q < 4; ++q) {
                int r = m0 + 16 * wid + hi * 4 + q;
                float o = 0.f;
                if (r < M) {
                    float rr = fsig(racc[ct][q] + b_r);
                    float uu = fsig(uacc[ct][q] + b_u);
                    float hterm = H0 ? b_hn : (nha[ct][q] + b_hn);
                    float nn = ftanh(nza[ct][q] + b_in + rr * hterm);
                    float hv = H0 ? 0.f : b2f(Hb[(size_t)r * 128 + c]);
                    o = (1.f - uu) * nn + uu * hv;
                    if (!FIN) HnB[(size_t)r * 128 + c] = f2b(o);
                }
                if (FIN) oo[ct][q] = o;
            }
        }
    };

#pragma unroll
    for (int h = 0; h < 2; ++h) {
#pragma unroll
        for (int j = 0; j < 4; ++j) {
            racc[j] = (f32x4)0.f; uacc[j] = (f32x4)0.f;
            nza[j] = (f32x4)0.f; nha[j] = (f32x4)0.f;
        }
#pragma unroll
        for (int kc = 0; kc < 4; ++kc) {
            bf16x8 zf;
#pragma unroll
            for (int g = 0; g < 3; ++g) {
                const int p = 8 + h * 12 + kc * 3 + g;
                if (!FIN && p == 31) asm volatile("s_waitcnt vmcnt(0)" ::: "memory");
                else                 asm volatile("s_waitcnt vmcnt(2)" ::: "memory");
                __builtin_amdgcn_s_barrier();
                if (p + 2 <= LAST) issue(p + 2);
                if (g == 0)
                    zf = *(const bf16x8*)&x_s[(arow * 16 + ((kc * 4 + hi) ^ (arow & 7))) * 8];
                const u16* buf = b_s[p % 3];
                __builtin_amdgcn_s_setprio(1);
#pragma unroll
                for (int jj = 0; jj < 4; ++jj) {
                    bf16x8 wi = *(const bf16x8*)&buf[((size_t)hi * 128 + jj * 16 + lo) * 8];
                    if (g == 0)      racc[jj] = __builtin_amdgcn_mfma_f32_16x16x32_bf16(zf, wi, racc[jj], 0, 0, 0);
                    else if (g == 1) uacc[jj] = __builtin_amdgcn_mfma_f32_16x16x32_bf16(zf, wi, uacc[jj], 0, 0, 0);
                    else             nza[jj]  = __builtin_amdgcn_mfma_f32_16x16x32_bf16(zf, wi, nza[jj], 0, 0, 0);
                    if (!H0) {
                        bf16x8 wh = *(const bf16x8*)&buf[((size_t)hi * 128 + 64 + jj * 16 + lo) * 8];
                        if (g == 0)      racc[jj] = __builtin_amdgcn_mfma_f32_16x16x32_bf16(hreg[kc], wh, racc[jj], 0, 0, 0);
                        else if (g == 1) uacc[jj] = __builtin_amdgcn_mfma_f32_16x16x32_bf16(hreg[kc], wh, uacc[jj], 0, 0, 0);
                        else             nha[jj]  = __builtin_amdgcn_mfma_f32_16x16x32_bf16(hreg[kc], wh, nha[jj], 0, 0, 0);
                    }
                }
                __builtin_amdgcn_s_setprio(0);
            }
        }
        epi(h, o_all[h]);
    }

    if (FIN) {
        // h' -> x_s (wave-private rows, same swizzle as z)
#pragma unroll
        for (int h = 0; h < 2; ++h)
#pragma unroll
            for (int ct = 0; ct < 4; ++ct) {
                int c = h * 64 + ct * 16 + lo;
#pragma unroll
                for (int q = 0; q < 4; ++q) {
                    int row = 16 * wid + hi * 4 + q;
                    int sl = c >> 3;
                    x_s[(row * 16 + (sl ^ (row & 7))) * 8 + (c & 7)] = f2b(o_all[h][ct][q]);
                }
            }
        // ---- F1: phases 32..35  y1 = relu(h' @ lW1 + lb1)
#pragma unroll
        for (int j = 0; j < 8; ++j) acc[j] = (f32x4)0.f;
#pragma unroll
        for (int ks = 0; ks < 4; ++ks) {
            const int p = 32 + ks;
            asm volatile("s_waitcnt vmcnt(2)" ::: "memory");
            __builtin_amdgcn_s_barrier();
            if (p + 2 <= 37) issue(p + 2);
            bf16x8 af = *(const bf16x8*)&x_s[(arow * 16 + ((ks * 4 + hi) ^ (arow & 7))) * 8];
            const u16* buf = b_s[p % 3];
            __builtin_amdgcn_s_setprio(1);
#pragma unroll
            for (int j = 0; j < 8; ++j) {
                bf16x8 bf = *(const bf16x8*)&buf[((size_t)hi * 128 + 16 * j + lo) * 8];
                acc[j] = __builtin_amdgcn_mfma_f32_16x16x32_bf16(af, bf, acc[j], 0, 0, 0);
            }
            __builtin_amdgcn_s_setprio(0);
        }
#pragma unroll
        for (int j = 0; j < 8; ++j) {
            int c = 16 * j + lo;
            float bv = lb1[c];
#pragma unroll
            for (int q = 0; q < 4; ++q) {
                int row = 16 * wid + hi * 4 + q;
                float v = fmaxf(acc[j][q] + bv, 0.f);
                int sl = c >> 3;
                x_s[(row * 16 + (sl ^ (row & 7))) * 8 + (c & 7)] = f2b(v);
            }
        }
        // ---- F2: phases 36..37  out = y1 @ lW2 + lb2  (NC=64)
        f32x4 a2[4];
#pragma unroll
        for (int j = 0; j < 4; ++j) a2[j] = (f32x4)0.f;
#pragma unroll
        for (int ph = 0; ph < 2; ++ph) {
            const int p = 36 + ph;
            if (p == 37) asm volatile("s_waitcnt vmcnt(0)" ::: "memory");
            else         asm volatile("s_waitcnt vmcnt(2)" ::: "memory");
            __builtin_amdgcn_s_barrier();
            const u16* buf = b_s[p % 3];
            __builtin_amdgcn_s_setprio(1);
#pragma unroll
            for (int k2 = 0; k2 < 2; ++k2) {
                int ks = ph * 2 + k2;
                bf16x8 af = *(const bf16x8*)&x_s[(arow * 16 + ((ks * 4 + hi) ^ (arow & 7))) * 8];
                int lk = k2 * 4 + hi;
#pragma unroll
                for (int jj = 0; jj < 4; ++jj) {
                    bf16x8 bf = *(const bf16x8*)&buf[((size_t)lk * 64 + 16 * jj + lo) * 8];
                    a2[jj] = __builtin_amdgcn_mfma_f32_16x16x32_bf16(af, bf, a2[jj], 0, 0, 0);
                }
            }
            __builtin_amdgcn_s_setprio(0);
        }
#pragma unroll
        for (int jj = 0; jj < 4; ++jj) {
            int c = 16 * jj + lo;
            float bv = lb2[c];
#pragma unroll
            for (int q = 0; q < 4; ++q) {
                int r = m0 + 16 * wid + hi * 4 + q;
                if (r < M) out[(size_t)r * 64 + c] = a2[jj][q] + bv;
            }
        }
    }
}

// ---------------------------------------------------------------------------
extern "C" void kernel_launch(void* const* d_in, const int* in_sizes, int n_in,
                              void* d_out, int out_size, void* d_ws, size_t ws_size,
                              hipStream_t stream) {
    const float* x   = (const float*)d_in[0];
    const int*   ei  = (const int*)d_in[1];
    const float* aW  = (const float*)d_in[2];
    const float* ab  = (const float*)d_in[3];
    const float* W1  = (const float*)d_in[4];
    const float* b1  = (const float*)d_in[5];
    const float* W2  = (const float*)d_in[6];
    const float* b2  = (const float*)d_in[7];
    const float* gam = (const float*)d_in[8];
    const float* bet = (const float*)d_in[9];
    const float* Wih = (const float*)d_in[10];
    const float* Whh = (const float*)d_in[11];
    const float* bih = (const float*)d_in[12];
    const float* bhh = (const float*)d_in[13];
    const float* lW1 = (const float*)d_in[14];
    const float* lb1 = (const float*)d_in[15];
    const float* lW2 = (const float*)d_in[16];
    const float* lb2 = (const float*)d_in[17];

    const int N = in_sizes[0] / 128;
    const int E = in_sizes[1] / 2;
    const int L = in_sizes[3] / 2;
    float* out = (float*)d_out;

    char* ws = (char*)d_ws;
    size_t off = 0;
    auto alloc = [&](size_t bytes) -> void* {
        void* p = ws + off;
        off = (off + bytes + 255) & ~(size_t)255;
        return p;
    };
    int* cnt  = (int*)alloc((size_t)N * 4);
    u16* adj  = (u16*)alloc((size_t)N * ADJ_CAP * 2);
    u16* tW1  = (u16*)alloc((size_t)L * 16384 * 2);
    u16* tW2  = (u16*)alloc((size_t)L * 16384 * 2);
    u16* tGRU = (u16*)alloc((size_t)98304 * 2);
    u16* tlW1 = (u16*)alloc((size_t)16384 * 2);
    u16* tlW2 = (u16*)alloc((size_t)8192 * 2);
    u16* xb   = (u16*)alloc((size_t)N * 128 * 2);
    u16* comb = (u16*)alloc((size_t)N * 128 * 2);
    u16* hAb  = (u16*)alloc((size_t)N * 128 * 2);
    (void)ws_size; (void)n_in; (void)out_size;

    hipMemsetAsync(cnt, 0, (size_t)N * 4, stream);

    const int EB = (E + 255) / 256;
    const int nwc = L * 4096 + 12288 + 3072;
    const int WB = (nwc + 255) / 256;
    const int FB = (N * 16 + 255) / 256;
    k_pro<<<EB * 8 + WB + FB, 256, 0, stream>>>(ei, cnt, adj, E, N,
                                                W1, W2, Wih, Whh, lW1, lW2,
                                                tW1, tW2, tGRU, tlW1, tlW2, L,
                                                x, xb, N * 16);

    const int mb = (N + 63) / 64;
    // layer 0 (h == 0): writes bf16 h only
    k_agg<<<(N + 3) / 4, 256, 0, stream>>>(xb, adj, cnt, aW, ab, comb, N);
    k_layer<true, false><<<mb, 256, 0, stream>>>(
        comb, nullptr, tW1, b1, tW2, b2, gam, bet,
        tGRU, bih, bhh, hAb,
        nullptr, nullptr, nullptr, nullptr, nullptr, N);
    // layer 1 + fused final MLP
    k_agg<<<(N + 3) / 4, 256, 0, stream>>>(hAb, adj, cnt, aW + 512, ab + 2, comb, N);
    k_layer<false, true><<<mb, 256, 0, stream>>>(
        comb, hAb, tW1 + 16384, b1 + 128, tW2 + 16384, b2 + 128,
        gam + 128, bet + 128, tGRU, bih, bhh, nullptr,
        tlW1, lb1, tlW2, lb2, out, N);
}

// Round 12
// 221.996 us; speedup vs baseline: 1.1037x; 1.1037x over previous
//
#include <hip/hip_runtime.h>
#include <math.h>

typedef unsigned short u16;
typedef __attribute__((ext_vector_type(8))) short bf16x8;
typedef __attribute__((ext_vector_type(4))) float f32x4;

#define ADJ_CAP 96   // padded CSR row capacity; Poisson(16) tail @96 ~ 0

__device__ __forceinline__ u16 f2b(float f) {
    union { float f; unsigned u; } v; v.f = f;
    unsigned r = (v.u + 0x7FFF + ((v.u >> 16) & 1)) >> 16;
    return (u16)r;
}
__device__ __forceinline__ float b2f(u16 h) {
    union { unsigned u; float f; } v; v.u = (unsigned)h << 16;
    return v.f;
}
__device__ __forceinline__ float u2f(unsigned u) {
    union { unsigned u; float f; } v; v.u = u;
    return v.f;
}
__device__ __forceinline__ float fsig(float x) { return 1.f / (1.f + __expf(-x)); }
__device__ __forceinline__ float ftanh(float x) {
    float e = __expf(2.f * x);
    return 1.f - 2.f / (e + 1.f);
}

__device__ __forceinline__ void gll16(const void* g, void* l) {
    __builtin_amdgcn_global_load_lds(
        (const __attribute__((address_space(1))) void*)g,
        (__attribute__((address_space(3))) void*)l, 16, 0, 0);
}

// ---------------- weight prep helper ----------------
__device__ __forceinline__ void conv_chunk(const float* __restrict__ src,
                                           u16* __restrict__ dst, int c, int NC) {
    int sl = c / NC, n = c - sl * NC;
    u16 tmp[8];
#pragma unroll
    for (int i = 0; i < 8; ++i) tmp[i] = f2b(src[(size_t)(sl * 8 + i) * NC + n]);
    *(uint4*)(dst + (size_t)c * 8) = *(const uint4*)tmp;
}

// ---------------- fused prologue: CSR build + weight prep + x->bf16 --------
__global__ void k_pro(const int* __restrict__ ei, int* __restrict__ cnt,
                      u16* __restrict__ adj, int E, int N,
                      const float* __restrict__ W1, const float* __restrict__ W2,
                      const float* __restrict__ Wih, const float* __restrict__ Whh,
                      const float* __restrict__ lW1, const float* __restrict__ lW2,
                      u16* __restrict__ tW1, u16* __restrict__ tW2,
                      u16* __restrict__ tGRU,
                      u16* __restrict__ tlW1, u16* __restrict__ tlW2, int L,
                      const float* __restrict__ x, u16* __restrict__ xb, int n8) {
    const int EB = (E + 255) >> 8;
    const int nwc = L * 4096 + 12288 + 3072;
    const int WB = (nwc + 255) >> 8;
    int b = blockIdx.x;
    if (b < EB * 8) {
        const int part = b & 7, chunk = b >> 3;
        const int span = (N + 7) >> 3;
        const int nlo = part * span;
        const int nhi = (nlo + span < N) ? nlo + span : N;
        int e = chunk * 256 + threadIdx.x;
        if (e < E) {
            int s = __builtin_nontemporal_load(&ei[e]);        // stream: don't evict adj lines
            int d = __builtin_nontemporal_load(&ei[E + e]);
            if (s >= nlo && s < nhi) {
                int p = atomicAdd(&cnt[s], 1);
                adj[(size_t)s * ADJ_CAP + p] = (u16)d;
            }
            if (d >= nlo && d < nhi) {
                int q = atomicAdd(&cnt[d], 1);
                adj[(size_t)d * ADJ_CAP + q] = (u16)s;
            }
        }
        return;
    }
    b -= EB * 8;
    if (b < WB) {
        int c = b * 256 + threadIdx.x;
        if (c >= nwc) return;
        if (c < L * 2048) { int l = c >> 11; conv_chunk(W1 + (size_t)l * 16384, tW1 + (size_t)l * 16384, c & 2047, 128); return; }
        c -= L * 2048;
        if (c < L * 2048) { int l = c >> 11; conv_chunk(W2 + (size_t)l * 16384, tW2 + (size_t)l * 16384, c & 2047, 128); return; }
        c -= L * 2048;
        if (c < 12288) {
            int s = c >> 9, r = c & 511;
            int q = r >> 7, mat = (r >> 6) & 1, cc = r & 63;
            int h = s / 12, s2 = s % 12, kc = s2 / 3, g = s2 % 3;
            int ocol = g * 128 + h * 64 + cc;
            const float* src = mat ? Whh : Wih;
            int kb = (kc * 4 + q) * 8;
            u16 tmp[8];
#pragma unroll
            for (int e = 0; e < 8; ++e) tmp[e] = f2b(src[(size_t)(kb + e) * 384 + ocol]);
            *(uint4*)(tGRU + (size_t)c * 8) = *(const uint4*)tmp;
            return;
        }
        c -= 12288;
        if (c < 2048) { conv_chunk(lW1, tlW1, c, 128); return; }
        c -= 2048;
        if (c < 1024) { conv_chunk(lW2, tlW2, c, 64); return; }
        return;
    }
    b -= WB;
    {
        int i = b * 256 + threadIdx.x;
        if (i < n8) {
            float4 a = *(const float4*)(x + (size_t)i * 8);
            float4 bb = *(const float4*)(x + (size_t)i * 8 + 4);
            u16 t[8] = {f2b(a.x), f2b(a.y), f2b(a.z), f2b(a.w),
                        f2b(bb.x), f2b(bb.y), f2b(bb.z), f2b(bb.w)};
            *(uint4*)(xb + (size_t)i * 8) = *(const uint4*)t;
        }
    }
}

// ---------------- aggregation: 16 lanes/row, 4 neighbors in parallel -------
__global__ __launch_bounds__(256) void k_agg(const u16* __restrict__ xb,
                                             const u16* __restrict__ adj,
                                             const int* __restrict__ cnt,
                                             const float* __restrict__ aW,
                                             const float* __restrict__ ab,
                                             u16* __restrict__ comb, int N) {
    int n = blockIdx.x * 4 + (threadIdx.x >> 6);
    if (n >= N) return;
    int l = threadIdx.x & 63;
    int grp = l >> 4;            // neighbor slot 0..3
    int f0 = (l & 15) * 8;       // 8 features per lane
    int beg = n * ADJ_CAP, deg = cnt[n], end = beg + deg;
    float s[8], m[8];
#pragma unroll
    for (int i = 0; i < 8; ++i) { s[i] = 0.f; m[i] = -3.402823e38f; }

    auto acc8 = [&](uint4 v) {
        unsigned d[4] = {v.x, v.y, v.z, v.w};
#pragma unroll
        for (int i = 0; i < 4; ++i) {
            float a0 = u2f(d[i] << 16);
            float a1 = u2f(d[i] & 0xFFFF0000u);
            s[2 * i] += a0;     m[2 * i] = fmaxf(m[2 * i], a0);
            s[2 * i + 1] += a1; m[2 * i + 1] = fmaxf(m[2 * i + 1], a1);
        }
    };

    int j = beg + grp;
    for (; j + 4 < end; j += 8) {
        int a0 = adj[j], a1 = adj[j + 4];
        uint4 v0 = *(const uint4*)(xb + (size_t)a0 * 128 + f0);
        uint4 v1 = *(const uint4*)(xb + (size_t)a1 * 128 + f0);
        acc8(v0);
        acc8(v1);
    }
    if (j < end) {
        int a = adj[j];
        uint4 v = *(const uint4*)(xb + (size_t)a * 128 + f0);
        acc8(v);
    }
#pragma unroll
    for (int i = 0; i < 8; ++i) {
        s[i] += __shfl_xor(s[i], 16);
        s[i] += __shfl_xor(s[i], 32);
        m[i] = fmaxf(m[i], __shfl_xor(m[i], 16));
        m[i] = fmaxf(m[i], __shfl_xor(m[i], 32));
    }
    if (deg == 0) {
#pragma unroll
        for (int i = 0; i < 8; ++i) m[i] = 0.f;
    }
    float p0 = 0.f, p1 = 0.f;
#pragma unroll
    for (int i = 0; i < 8; ++i) {
        float2 wS = *(const float2*)(aW + (size_t)(f0 + i) * 2);
        float2 wM = *(const float2*)(aW + (size_t)(128 + f0 + i) * 2);
        p0 += s[i] * wS.x + m[i] * wM.x;
        p1 += s[i] * wS.y + m[i] * wM.y;
    }
#pragma unroll
    for (int o = 8; o; o >>= 1) { p0 += __shfl_xor(p0, o); p1 += __shfl_xor(p1, o); }
    p0 += ab[0]; p1 += ab[1];
    float pm = fmaxf(p0, p1);
    float ea = __expf(p0 - pm), eb = __expf(p1 - pm);
    float w0 = ea / (ea + eb), w1 = 1.f - w0;
    if (grp == 0) {
        uint4 xv = *(const uint4*)(xb + (size_t)n * 128 + f0);
        unsigned xs[4] = {xv.x, xv.y, xv.z, xv.w};
        unsigned dw[4];
#pragma unroll
        for (int i = 0; i < 4; ++i) {
            float xlo = u2f(xs[i] << 16), xhi = u2f(xs[i] & 0xFFFF0000u);
            float olo = xlo + w0 * s[2 * i] + w1 * m[2 * i];
            float ohi = xhi + w0 * s[2 * i + 1] + w1 * m[2 * i + 1];
            dw[i] = (unsigned)f2b(olo) | ((unsigned)f2b(ohi) << 16);
        }
        uint4 o4 = make_uint4(dw[0], dw[1], dw[2], dw[3]);
        *(uint4*)(comb + (size_t)n * 128 + f0) = o4;
    }
}

// ---------------- fused layer, counted-vmcnt pipeline -----------------------
// 128 rows/block, 512 threads (8 waves). 32 stages of 8 KB, ring-3, 1 stage
// in flight (vmcnt(1): 1 gll16/wave/stage). LDS 32+24 = 56 KB -> 2 blocks/CU.
// Halves the per-phase L2 weight-broadcast traffic vs 64-row blocks (R11
// analysis: 580 cyc/phase L2 floor was the binding constraint).
template <bool H0>
__global__ __launch_bounds__(512, 4) void k_layer(
    const u16* __restrict__ Cb, const u16* __restrict__ Hb,
    const u16* __restrict__ W1t, const float* __restrict__ b1,
    const u16* __restrict__ W2t, const float* __restrict__ b2,
    const float* __restrict__ gam, const float* __restrict__ bet,
    const u16* __restrict__ tG,
    const float* __restrict__ bih, const float* __restrict__ bhh,
    u16* __restrict__ HnB, int M) {
    __shared__ __align__(16) u16 x_s[128 * 16 * 8];  // 32 KB: comb -> z1 -> z
    __shared__ __align__(16) u16 b_s[3][4096];       // 3 x 8 KB weight ring
    const int t = threadIdx.x;
    const int m0 = blockIdx.x * 128;
    const int wid = t >> 6, lane = t & 63, lo = lane & 15, hi = lane >> 4;
    const int arow = 16 * wid + lo;

    auto issue = [&](int s) {   // stage 8 KB: 1 gll16 per wave (8 waves x 1 KB)
        const u16* g = (s < 4) ? (W1t + (size_t)s * 4096)
                     : (s < 8) ? (W2t + (size_t)(s - 4) * 4096)
                               : (tG + (size_t)(s - 8) * 4096);
        char* l = (char*)b_s[s % 3] + wid * 1024;
        const char* gp = (const char*)g + wid * 1024 + lane * 16;
        gll16(gp, l);
    };

    // ---- prologue: biases -> regs, x_s stage, stages 0/1
    float b1r[8], g2r[8], t2r[8];
#pragma unroll
    for (int j = 0; j < 8; ++j) {
        int c = 16 * j + lo;
        b1r[j] = b1[c];
        float gv = gam[c];
        g2r[j] = gv;
        t2r[j] = b2[c] * gv + bet[c];
    }
#pragma unroll
    for (int i = 0; i < 4; ++i) {
        int off = (i * 8 + wid) * 1024;       // bytes into x_s (32 KB total)
        int row = (off >> 8) + (lane >> 4);   // 256 B per row
        int sl = lane & 15;
        int gr = m0 + row; gr = gr < M ? gr : M - 1;
        gll16(Cb + (size_t)gr * 128 + ((sl ^ (row & 7)) * 8), (char*)x_s + off);
    }
    issue(0);
    issue(1);

    f32x4 acc[8];
#pragma unroll
    for (int j = 0; j < 8; ++j) acc[j] = (f32x4)0.f;

    // ---- GEMM1: phases 0..3
#pragma unroll
    for (int ks = 0; ks < 4; ++ks) {
        const int p = ks;
        asm volatile("s_waitcnt vmcnt(1)" ::: "memory");
        __builtin_amdgcn_s_barrier();
        issue(p + 2);
        bf16x8 af = *(const bf16x8*)&x_s[(arow * 16 + ((ks * 4 + hi) ^ (arow & 7))) * 8];
        const u16* buf = b_s[p % 3];
        __builtin_amdgcn_s_setprio(1);
#pragma unroll
        for (int j = 0; j < 8; ++j) {
            bf16x8 bf = *(const bf16x8*)&buf[((size_t)hi * 128 + 16 * j + lo) * 8];
            acc[j] = __builtin_amdgcn_mfma_f32_16x16x32_bf16(af, bf, acc[j], 0, 0, 0);
        }
        __builtin_amdgcn_s_setprio(0);
    }
    // z1 epilogue -> x_s (wave-private rows; biases preloaded, no VMEM)
#pragma unroll
    for (int j = 0; j < 8; ++j) {
        int c = 16 * j + lo;
#pragma unroll
        for (int q = 0; q < 4; ++q) {
            int row = 16 * wid + hi * 4 + q;
            float v = fmaxf(acc[j][q] + b1r[j], 0.f);
            int sl = c >> 3;
            x_s[(row * 16 + (sl ^ (row & 7))) * 8 + (c & 7)] = f2b(v);
        }
        acc[j] = (f32x4)0.f;
    }

    // ---- GEMM2: phases 4..7
#pragma unroll
    for (int ks = 0; ks < 4; ++ks) {
        const int p = 4 + ks;
        asm volatile("s_waitcnt vmcnt(1)" ::: "memory");
        __builtin_amdgcn_s_barrier();
        issue(p + 2);
        bf16x8 af = *(const bf16x8*)&x_s[(arow * 16 + ((ks * 4 + hi) ^ (arow & 7))) * 8];
        const u16* buf = b_s[p % 3];
        __builtin_amdgcn_s_setprio(1);
#pragma unroll
        for (int j = 0; j < 8; ++j) {
            bf16x8 bf = *(const bf16x8*)&buf[((size_t)hi * 128 + 16 * j + lo) * 8];
            acc[j] = __builtin_amdgcn_mfma_f32_16x16x32_bf16(af, bf, acc[j], 0, 0, 0);
        }
        __builtin_amdgcn_s_setprio(0);
    }
    // z epilogue -> x_s (folded BN, no VMEM)
#pragma unroll
    for (int j = 0; j < 8; ++j) {
        int c = 16 * j + lo;
#pragma unroll
        for (int q = 0; q < 4; ++q) {
            int row = 16 * wid + hi * 4 + q;
            float v = acc[j][q] * g2r[j] + t2r[j];
            int sl = c >> 3;
            x_s[(row * 16 + (sl ^ (row & 7))) * 8 + (c & 7)] = f2b(v);
        }
    }
    // h -> regs, deferred to here (GEMM region stays low-pressure)
    bf16x8 hreg[4];
    if (!H0) {
        int gr = m0 + arow; gr = gr < M ? gr : M - 1;
#pragma unroll
        for (int kc = 0; kc < 4; ++kc)
            hreg[kc] = *(const bf16x8*)(Hb + (size_t)gr * 128 + (kc * 4 + hi) * 8);
    }

    // ---- GRU: phases 8..31
    f32x4 racc[4], uacc[4], nza[4], nha[4];

    auto epi = [&](int h) {
#pragma unroll
        for (int ct = 0; ct < 4; ++ct) {
            int c = h * 64 + ct * 16 + lo;
            float b_r = bih[c] + bhh[c];
            float b_u = bih[c + 128] + bhh[c + 128];
            float b_in = bih[c + 256], b_hn = bhh[c + 256];
#pragma unroll
            for (int q = 0; q < 4; ++q) {
                int r = m0 + 16 * wid + hi * 4 + q;
                if (r < M) {
                    float rr = fsig(racc[ct][q] + b_r);
                    float uu = fsig(uacc[ct][q] + b_u);
                    float hterm = H0 ? b_hn : (nha[ct][q] + b_hn);
                    float nn = ftanh(nza[ct][q] + b_in + rr * hterm);
                    float hv = H0 ? 0.f : b2f(Hb[(size_t)r * 128 + c]);
                    float o = (1.f - uu) * nn + uu * hv;
                    HnB[(size_t)r * 128 + c] = f2b(o);
                }
            }
        }
    };

#pragma unroll
    for (int h = 0; h < 2; ++h) {
#pragma unroll
        for (int j = 0; j < 4; ++j) {
            racc[j] = (f32x4)0.f; uacc[j] = (f32x4)0.f;
            nza[j] = (f32x4)0.f; nha[j] = (f32x4)0.f;
        }
#pragma unroll
        for (int kc = 0; kc < 4; ++kc) {
            bf16x8 zf;
#pragma unroll
            for (int g = 0; g < 3; ++g) {
                const int p = 8 + h * 12 + kc * 3 + g;
                if (p == 31) asm volatile("s_waitcnt vmcnt(0)" ::: "memory");
                else         asm volatile("s_waitcnt vmcnt(1)" ::: "memory");
                __builtin_amdgcn_s_barrier();
                if (p + 2 <= 31) issue(p + 2);
                if (g == 0)
                    zf = *(const bf16x8*)&x_s[(arow * 16 + ((kc * 4 + hi) ^ (arow & 7))) * 8];
                const u16* buf = b_s[p % 3];
                __builtin_amdgcn_s_setprio(1);
#pragma unroll
                for (int jj = 0; jj < 4; ++jj) {
                    bf16x8 wi = *(const bf16x8*)&buf[((size_t)hi * 128 + jj * 16 + lo) * 8];
                    if (g == 0)      racc[jj] = __builtin_amdgcn_mfma_f32_16x16x32_bf16(zf, wi, racc[jj], 0, 0, 0);
                    else if (g == 1) uacc[jj] = __builtin_amdgcn_mfma_f32_16x16x32_bf16(zf, wi, uacc[jj], 0, 0, 0);
                    else             nza[jj]  = __builtin_amdgcn_mfma_f32_16x16x32_bf16(zf, wi, nza[jj], 0, 0, 0);
                    if (!H0) {
                        bf16x8 wh = *(const bf16x8*)&buf[((size_t)hi * 128 + 64 + jj * 16 + lo) * 8];
                        if (g == 0)      racc[jj] = __builtin_amdgcn_mfma_f32_16x16x32_bf16(hreg[kc], wh, racc[jj], 0, 0, 0);
                        else if (g == 1) uacc[jj] = __builtin_amdgcn_mfma_f32_16x16x32_bf16(hreg[kc], wh, uacc[jj], 0, 0, 0);
                        else             nha[jj]  = __builtin_amdgcn_mfma_f32_16x16x32_bf16(hreg[kc], wh, nha[jj], 0, 0, 0);
                    }
                }
                __builtin_amdgcn_s_setprio(0);
            }
        }
        epi(h);
    }
}

// ---------------- fused final MLP: out = relu(h@lW1+lb1)@lW2 + lb2 --------
__global__ __launch_bounds__(256, 2) void k_final(const u16* __restrict__ Hb,
                                                  const u16* __restrict__ W1t,
                                                  const float* __restrict__ b1,
                                                  const u16* __restrict__ W2t,
                                                  const float* __restrict__ b2,
                                                  float* __restrict__ out, int M) {
    __shared__ __align__(16) u16 x_s[64 * 16 * 8];
    __shared__ __align__(16) u16 w_s[16 * 128 * 8];
    const int t = threadIdx.x;
    const int m0 = blockIdx.x * 64;
    const int w = t >> 6, l = t & 63, lo = l & 15, hi = l >> 4;
    const int arow = 16 * w + lo;
#pragma unroll
    for (int i = 0; i < 4; ++i) {
        int idx = t + i * 256;
        int row = idx >> 4, sl = idx & 15;
        int gr = m0 + row; gr = gr < M ? gr : M - 1;
        *(uint4*)&x_s[(row * 16 + (sl ^ (row & 7))) * 8] =
            *(const uint4*)(Hb + (size_t)gr * 128 + sl * 8);
    }
#pragma unroll
    for (int i = 0; i < 8; ++i) {
        int idx = t + i * 256;
        *(uint4*)&w_s[idx * 8] = *(const uint4*)(W1t + (size_t)idx * 8);
    }
    __syncthreads();
    f32x4 acc[8];
#pragma unroll
    for (int j = 0; j < 8; ++j) acc[j] = (f32x4)0.f;
#pragma unroll
    for (int ks = 0; ks < 4; ++ks) {
        bf16x8 af = *(const bf16x8*)&x_s[(arow * 16 + ((ks * 4 + hi) ^ (arow & 7))) * 8];
#pragma unroll
        for (int j = 0; j < 8; ++j) {
            bf16x8 bf = *(const bf16x8*)&w_s[((ks * 4 + hi) * 128 + 16 * j + lo) * 8];
            acc[j] = __builtin_amdgcn_mfma_f32_16x16x32_bf16(af, bf, acc[j], 0, 0, 0);
        }
    }
    __syncthreads();
#pragma unroll
    for (int j = 0; j < 8; ++j) {
        int c = 16 * j + lo;
        float bv = b1[c];
#pragma unroll
        for (int q = 0; q < 4; ++q) {
            int row = 16 * w + hi * 4 + q;
            float v = fmaxf(acc[j][q] + bv, 0.f);
            int sl = c >> 3;
            x_s[(row * 16 + (sl ^ (row & 7))) * 8 + (c & 7)] = f2b(v);
        }
    }
#pragma unroll
    for (int i = 0; i < 4; ++i) {
        int idx = t + i * 256;
        *(uint4*)&w_s[idx * 8] = *(const uint4*)(W2t + (size_t)idx * 8);
    }
    __syncthreads();
    f32x4 a2[4];
#pragma unroll
    for (int j = 0; j < 4; ++j) a2[j] = (f32x4)0.f;
#pragma unroll
    for (int ks = 0; ks < 4; ++ks) {
        bf16x8 af = *(const bf16x8*)&x_s[(arow * 16 + ((ks * 4 + hi) ^ (arow & 7))) * 8];
#pragma unroll
        for (int j = 0; j < 4; ++j) {
            bf16x8 bf = *(const bf16x8*)&w_s[((ks * 4 + hi) * 64 + 16 * j + lo) * 8];
            a2[j] = __builtin_amdgcn_mfma_f32_16x16x32_bf16(af, bf, a2[j], 0, 0, 0);
        }
    }
#pragma unroll
    for (int j = 0; j < 4; ++j) {
        int c = 16 * j + lo;
        float bv = b2[c];
#pragma unroll
        for (int q = 0; q < 4; ++q) {
            int r = m0 + 16 * w + hi * 4 + q;
            if (r < M) out[(size_t)r * 64 + c] = a2[j][q] + bv;
        }
    }
}

// ---------------------------------------------------------------------------
extern "C" void kernel_launch(void* const* d_in, const int* in_sizes, int n_in,
                              void* d_out, int out_size, void* d_ws, size_t ws_size,
                              hipStream_t stream) {
    const float* x   = (const float*)d_in[0];
    const int*   ei  = (const int*)d_in[1];
    const float* aW  = (const float*)d_in[2];
    const float* ab  = (const float*)d_in[3];
    const float* W1  = (const float*)d_in[4];
    const float* b1  = (const float*)d_in[5];
    const float* W2  = (const float*)d_in[6];
    const float* b2  = (const float*)d_in[7];
    const float* gam = (const float*)d_in[8];
    const float* bet = (const float*)d_in[9];
    const float* Wih = (const float*)d_in[10];
    const float* Whh = (const float*)d_in[11];
    const float* bih = (const float*)d_in[12];
    const float* bhh = (const float*)d_in[13];
    const float* lW1 = (const float*)d_in[14];
    const float* lb1 = (const float*)d_in[15];
    const float* lW2 = (const float*)d_in[16];
    const float* lb2 = (const float*)d_in[17];

    const int N = in_sizes[0] / 128;
    const int E = in_sizes[1] / 2;
    const int L = in_sizes[3] / 2;
    float* out = (float*)d_out;

    char* ws = (char*)d_ws;
    size_t off = 0;
    auto alloc = [&](size_t bytes) -> void* {
        void* p = ws + off;
        off = (off + bytes + 255) & ~(size_t)255;
        return p;
    };
    int* cnt  = (int*)alloc((size_t)N * 4);
    u16* adj  = (u16*)alloc((size_t)N * ADJ_CAP * 2);
    u16* tW1  = (u16*)alloc((size_t)L * 16384 * 2);
    u16* tW2  = (u16*)alloc((size_t)L * 16384 * 2);
    u16* tGRU = (u16*)alloc((size_t)98304 * 2);
    u16* tlW1 = (u16*)alloc((size_t)16384 * 2);
    u16* tlW2 = (u16*)alloc((size_t)8192 * 2);
    u16* xb   = (u16*)alloc((size_t)N * 128 * 2);
    u16* comb = (u16*)alloc((size_t)N * 128 * 2);
    u16* hAb  = (u16*)alloc((size_t)N * 128 * 2);
    u16* hBb  = (u16*)alloc((size_t)N * 128 * 2);
    (void)ws_size; (void)n_in; (void)out_size;

    hipMemsetAsync(cnt, 0, (size_t)N * 4, stream);

    const int EB = (E + 255) / 256;
    const int nwc = L * 4096 + 12288 + 3072;
    const int WB = (nwc + 255) / 256;
    const int FB = (N * 16 + 255) / 256;
    k_pro<<<EB * 8 + WB + FB, 256, 0, stream>>>(ei, cnt, adj, E, N,
                                                W1, W2, Wih, Whh, lW1, lW2,
                                                tW1, tW2, tGRU, tlW1, tlW2, L,
                                                x, xb, N * 16);

    const int mb = (N + 127) / 128;
    // layer 0 (h == 0)
    k_agg<<<(N + 3) / 4, 256, 0, stream>>>(xb, adj, cnt, aW, ab, comb, N);
    k_layer<true><<<mb, 512, 0, stream>>>(
        comb, nullptr, tW1, b1, tW2, b2, gam, bet,
        tGRU, bih, bhh, hAb, N);
    // layer 1
    k_agg<<<(N + 3) / 4, 256, 0, stream>>>(hAb, adj, cnt, aW + 512, ab + 2, comb, N);
    k_layer<false><<<mb, 512, 0, stream>>>(
        comb, hAb, tW1 + 16384, b1 + 128, tW2 + 16384, b2 + 128,
        gam + 128, bet + 128, tGRU, bih, bhh, hBb, N);

    k_final<<<(N + 63) / 64, 256, 0, stream>>>(hBb, tlW1, lb1, tlW2, lb2, out, N);
}